// Round 5
// baseline (134.046 us; speedup 1.0000x reference)
//
#include <hip/hip_runtime.h>

#define EPSF 1e-12f
#define STILE 256              // splines per block
#define KK 64
#define SPW 130                // words per spline: 64 x {y,d} 8B pairs + 2 pad
#define BLK 1024
#define NWAVE (BLK / 64)       // 16 waves
#define PRELOOP ((STILE * KK) / BLK)   // 16

__device__ __forceinline__ float sgnf(float x) {
    return (x > 0.f) ? 1.f : ((x < 0.f) ? -1.f : 0.f);
}

// Compact fused PCHIP: LDS holds {y,d} pairs (8B/knot) for 256 splines ->
// wave-level global accesses are 1KB contiguous. Power-basis conversion done
// per-element on the fly (uniform knot spacing -> h is a scalar constant).
__global__ __launch_bounds__(BLK, 4) void pchip_fused6(
    const float* __restrict__ xq,
    const float* __restrict__ coeffs,
    const float* __restrict__ knots,
    float* __restrict__ out,
    int S, int b_chunk, int n_stile)
{
    __shared__ float lds[STILE * SPW];   // 133120 B
    __shared__ float skn[KK];

    int tid = threadIdx.x;

    // XCD-banded swizzle: XCD g owns n_stile/8 consecutive s-tiles (all b-tiles)
    // -> its L2 aggregates a contiguous column band; evictions emit longer runs.
    int bid = blockIdx.x;
    int s_tile, b_tile;
    if ((n_stile & 7) == 0) {
        int xcd = bid & 7, w = bid >> 3;
        int spx = n_stile >> 3;
        s_tile = xcd * spx + (w % spx);
        b_tile = w / spx;
    } else {
        s_tile = bid % n_stile;
        b_tile = bid / n_stile;
    }
    int s0 = s_tile * STILE;
    int b0 = b_tile * b_chunk;

    if (tid < KK) skn[tid] = knots[tid];

    // stage y into even slots (float4 global reads, coalesced)
#pragma unroll
    for (int i = 0; i < PRELOOP / 4; i++) {
        int p = (tid + i * BLK) << 2;          // 4 consecutive k per thread
        int sl = p >> 6, k = p & 63;
        float4 v = *(const float4*)(coeffs + (size_t)(s0 + sl) * KK + k);
        int wb = sl * SPW + 2 * k;
        lds[wb] = v.x; lds[wb + 2] = v.y; lds[wb + 4] = v.z; lds[wb + 6] = v.w;
    }
    __syncthreads();

    float x0d = skn[0], x1d = skn[KK - 1];
    float hraw = (x1d - x0d) / (float)(KK - 1);   // uniform knot spacing
    float he = hraw + EPSF;

    // delta[k] -> odd slot (k < 63); reads even slots only (no hazard)
#pragma unroll
    for (int i = 0; i < PRELOOP; i++) {
        int p = tid + i * BLK;
        int sl = p >> 6, k = p & 63;
        if (k < KK - 1) {
            int wb = sl * SPW + 2 * k;
            lds[wb + 1] = (lds[wb + 2] - lds[wb]) / he;
        }
    }
    __syncthreads();

    // Fritsch-Carlson slopes (reads odd slots) -> regs -> sync -> odd slots
    float dreg[PRELOOP];
#pragma unroll
    for (int i = 0; i < PRELOOP; i++) {
        int p = tid + i * BLK;
        int sl = p >> 6, k = p & 63;
        const float* del = lds + sl * SPW;     // delta[k] at del[2k+1]
        float d;
        if (k == 0) {
            float de0 = del[1], de1 = del[3];
            d = ((2.f * hraw + hraw) * de0 - hraw * de1) / (hraw + hraw + EPSF);
            if (sgnf(d) != sgnf(de0)) d = 0.f;
            if ((sgnf(de0) != sgnf(de1)) && (fabsf(d) > 3.f * fabsf(de0))) d = 3.f * de0;
        } else if (k == KK - 1) {
            float dn1 = del[2 * (KK - 2) + 1], dn2 = del[2 * (KK - 3) + 1];
            d = ((2.f * hraw + hraw) * dn1 - hraw * dn2) / (hraw + hraw + EPSF);
            if (sgnf(d) != sgnf(dn1)) d = 0.f;
            if ((sgnf(dn1) != sgnf(dn2)) && (fabsf(d) > 3.f * fabsf(dn1))) d = 3.f * dn1;
        } else {
            float dprev = del[2 * k - 1], dnext = del[2 * k + 1];
            bool same = dprev * dnext > 0.f;
            float w1 = 2.f * hraw + hraw;      // 2*h_next + h_prev (uniform)
            float w2 = hraw + 2.f * hraw;
            float denom = w1 / (dprev + EPSF) + w2 / (dnext + EPSF);
            float dint = (w1 + w2) / (denom + EPSF);
            d = same ? dint : 0.f;
        }
        dreg[i] = d;
    }
    __syncthreads();
#pragma unroll
    for (int i = 0; i < PRELOOP; i++) {
        int p = tid + i * BLK;
        int sl = p >> 6, k = p & 63;
        lds[sl * SPW + 2 * k + 1] = dreg[i];
    }
    __syncthreads();

    // ---- evaluation sweep: lane owns 4 consecutive splines; wave accesses
    //      1KB contiguous per row (64 lanes x float4). Normal stores (L2 WB). ----
    float af = (float)(KK - 1) / (x1d - x0d);
    float bf = -x0d * af;
    int wv = tid >> 6, lane = tid & 63;
    const float* qb = lds + (lane << 2) * SPW;

    int rpw = b_chunk / NWAVE;
    size_t off = (size_t)(b0 + wv * rpw) * S + s0 + (lane << 2);
    for (int r = 0; r < rpw; r++) {
        float4 xv = *(const float4*)(xq + off);
        float xs[4] = {xv.x, xv.y, xv.z, xv.w};
        float rr[4];
#pragma unroll
        for (int j = 0; j < 4; j++) {
            float tf = fmaf(xs[j], af, bf);
            float tc = fminf(fmaxf(tf, 0.f), (float)(KK - 1));
            int idx = min((int)tc, KK - 2);
            float t = tc - (float)idx;
            float ext = tf - tc;               // 0 in range, linear extrap outside
            const float2* e = (const float2*)(qb + j * SPW + 2 * idx);
            float2 e0 = e[0], e1 = e[1];       // {y0,d0},{y1,d1}: 2x ds_read_b64
            float m0 = he * e0.y, m1 = he * e1.y;
            float dy = e1.x - e0.x;
            float c2 = fmaf(3.f, dy, -(m0 + m0 + m1));   // 3dy - 2m0 - m1
            float c3 = m0 + m1 - dy - dy;                // m0 + m1 - 2dy
            float P  = fmaf(fmaf(fmaf(c3, t, c2), t, m0), t, e0.x);
            float wd = fmaf(fmaf(t, 2.f, t), c3, c2 + c2); // 3t*c3 + 2c2
            float Pp = fmaf(t, wd, m0);
            rr[j] = fmaf(Pp, ext, P);
        }
        *(float4*)(out + off) = make_float4(rr[0], rr[1], rr[2], rr[3]);
        off += (size_t)S;
    }
}

extern "C" void kernel_launch(void* const* d_in, const int* in_sizes, int n_in,
                              void* d_out, int out_size, void* d_ws, size_t ws_size,
                              hipStream_t stream) {
    const float* xq     = (const float*)d_in[0];
    const float* coeffs = (const float*)d_in[1];
    const float* knots  = (const float*)d_in[2];
    float* out = (float*)d_out;

    int K = in_sizes[2];           // 64
    int S = in_sizes[1] / K;       // 4096
    int N = in_sizes[0];           // B*S
    int B = N / S;                 // 4096

    int NS = S / STILE;            // 16 s-tiles
    int b_chunk = 256;             // rows per block (16 rows/wave)
    int NB = B / b_chunk;          // 16 b-tiles
    dim3 grid(NS * NB);            // 256 blocks = 1 per CU
    pchip_fused6<<<grid, BLK, 0, stream>>>(xq, coeffs, knots, out, S, b_chunk, NS);
}

// Round 6
// 125.757 us; speedup vs baseline: 1.0659x; 1.0659x over previous
//
#include <hip/hip_runtime.h>

#define EPSF 1e-12f
#define STILE 64
#define KK 64
#define RSTR 65                 // row stride in float4 units (1040 B)
#define FSTR (4 * RSTR)         // 260 floats per coefficient row
#define BLK 1024
#define NWAVE (BLK / 64)        // 16 waves
#define PRELOOP ((STILE * KK) / BLK)  // 4
#define DEPTH 4                 // outstanding row-pair loads per wave

__device__ __forceinline__ float sgnf(float x) {
    return (x > 0.f) ? 1.f : ((x < 0.f) ? -1.f : 0.f);
}

// One ds_read_b128 per element: cf[row] holds {c0,c1,c2,c3} per interval.
__device__ __forceinline__ float eval1(float x, const float4* __restrict__ q,
                                       float af, float bf) {
    float tf = fmaf(x, af, bf);
    float tcf = fminf(fmaxf(tf, 0.f), (float)(KK - 1));
    int idx = min((int)tcf, KK - 2);
    float t = tcf - (float)idx;
    float4 c = q[idx];
    float P = fmaf(fmaf(fmaf(c.w, t, c.z), t, c.y), t, c.x);
    float w = fmaf(fmaf(t, 2.f, t), c.w, c.z + c.z);  // 3t*c3 + 2c2
    float Pp = fmaf(t, w, c.y);                       // P'(t)
    return fmaf(Pp, tf - tcf, P);                     // branch-free extrapolation
}

__global__ __launch_bounds__(BLK, 8) void pchip_fused7(
    const float* __restrict__ xq,
    const float* __restrict__ coeffs,
    const float* __restrict__ knots,
    float* __restrict__ out,
    int S, int b_chunk)
{
    __shared__ float4 cf4[STILE * RSTR];   // 66560 B: interleaved c0..c3
    __shared__ float skn[KK];
    float* cf = (float*)cf4;

    int tid = threadIdx.x;
    int s0 = blockIdx.x * STILE;
    int b0 = blockIdx.y * b_chunk;

    if (tid < KK) skn[tid] = knots[tid];
    // stage y into slot 0 (coalesced global read)
#pragma unroll
    for (int i = 0; i < PRELOOP; i++) {
        int p = tid + i * BLK;
        int sl = p >> 6, k = p & 63;
        cf[sl * FSTR + 4 * k] = coeffs[(size_t)(s0 + sl) * KK + k];
    }
    __syncthreads();
    // delta[k] into slot 3 (reads slot 0 only)
#pragma unroll
    for (int i = 0; i < PRELOOP; i++) {
        int p = tid + i * BLK;
        int sl = p >> 6, k = p & 63;
        if (k < KK - 1) {
            int ib = sl * FSTR + 4 * k;
            float hh = skn[k + 1] - skn[k];
            cf[ib + 3] = (cf[ib + 4] - cf[ib]) / (hh + EPSF);
        }
    }
    __syncthreads();
    // Fritsch-Carlson slopes d into slot 2 (reads slot 3 only)
#pragma unroll
    for (int i = 0; i < PRELOOP; i++) {
        int p = tid + i * BLK;
        int sl = p >> 6, k = p & 63;
        int rb = sl * FSTR;
        float d;
        if (k == 0) {
            float h0 = skn[1] - skn[0], h1 = skn[2] - skn[1];
            float de0 = cf[rb + 3], de1 = cf[rb + 7];
            d = ((2.f * h0 + h1) * de0 - h0 * de1) / (h0 + h1 + EPSF);
            if (sgnf(d) != sgnf(de0)) d = 0.f;
            if ((sgnf(de0) != sgnf(de1)) && (fabsf(d) > 3.f * fabsf(de0))) d = 3.f * de0;
        } else if (k == KK - 1) {
            float hn1 = skn[KK - 1] - skn[KK - 2], hn2 = skn[KK - 2] - skn[KK - 3];
            float dn1 = cf[rb + 4 * (KK - 2) + 3], dn2 = cf[rb + 4 * (KK - 3) + 3];
            d = ((2.f * hn1 + hn2) * dn1 - hn1 * dn2) / (hn1 + hn2 + EPSF);
            if (sgnf(d) != sgnf(dn1)) d = 0.f;
            if ((sgnf(dn1) != sgnf(dn2)) && (fabsf(d) > 3.f * fabsf(dn1))) d = 3.f * dn1;
        } else {
            float dprev = cf[rb + 4 * (k - 1) + 3], dnext = cf[rb + 4 * k + 3];
            float hp = skn[k] - skn[k - 1], hn = skn[k + 1] - skn[k];
            bool same = dprev * dnext > 0.f;
            float w1 = 2.f * hn + hp;
            float w2 = hn + 2.f * hp;
            float denom = w1 / (dprev + EPSF) + w2 / (dnext + EPSF);
            float dint = (w1 + w2) / (denom + EPSF);
            d = same ? dint : 0.f;
        }
        cf[rb + 4 * k + 2] = d;
    }
    __syncthreads();
    // power-basis conversion: read y(k),y(k+1),d(k),d(k+1) -> regs, sync, write c1..c3
    float c1r[PRELOOP], c2r[PRELOOP], c3r[PRELOOP];
#pragma unroll
    for (int i = 0; i < PRELOOP; i++) {
        int p = tid + i * BLK;
        int sl = p >> 6, k = p & 63;
        int kc = min(k, KK - 2);
        int ib = sl * FSTR + 4 * kc;
        float y0 = cf[ib], y1 = cf[ib + 4];
        float d0 = cf[ib + 2], d1 = cf[ib + 6];
        float h = skn[kc + 1] - skn[kc] + EPSF;
        c1r[i] = h * d0;
        c2r[i] = 3.f * (y1 - y0) - h * (2.f * d0 + d1);
        c3r[i] = 2.f * (y0 - y1) + h * (d0 + d1);
    }
    __syncthreads();
#pragma unroll
    for (int i = 0; i < PRELOOP; i++) {
        int p = tid + i * BLK;
        int sl = p >> 6, k = p & 63;
        if (k < KK - 1) {
            int ib = sl * FSTR + 4 * k;
            cf[ib + 1] = c1r[i];
            cf[ib + 2] = c2r[i];
            cf[ib + 3] = c3r[i];
        }
    }
    __syncthreads();

    // ---- evaluation sweep: wave = 2 b-rows x 64 s-cols, float2 per lane ----
    // DEPTH=4 independent row-pair loads issued before any consumption (pinned
    // by sched_barrier) -> 4 outstanding global loads per wave, 4x in-flight
    // bytes vs R1. Consumption per pair: prep, 2x ds_read_b128, Horner, store.
    float x0d = skn[0], x1d = skn[KK - 1];
    float invh = (float)(KK - 1) / (x1d - x0d);
    float af = invh, bf = -x0d * invh;
    int wave = tid >> 6, lane = tid & 63;
    int brow = lane >> 5;            // 0..1
    int scol = (lane & 31) << 1;     // 0,2,..,62
    const float4* q0 = cf4 + scol * RSTR;
    const float4* q1 = q0 + RSTR;

    int rpw = b_chunk / NWAVE;       // 32 rows per wave
    int nb = rpw >> 1;               // 16 two-row batches
    size_t off = (size_t)(b0 + wave * rpw + brow) * S + s0 + scol;
    const size_t step = (size_t)2 * S;

    for (int ii = 0; ii < nb; ii += DEPTH) {
        float2 xv[DEPTH];
#pragma unroll
        for (int u = 0; u < DEPTH; u++)
            xv[u] = *(const float2*)(xq + off + (size_t)u * step);
        __builtin_amdgcn_sched_barrier(0);   // loads stay issued above this point
#pragma unroll
        for (int u = 0; u < DEPTH; u++) {
            float2 r;
            r.x = eval1(xv[u].x, q0, af, bf);
            r.y = eval1(xv[u].y, q1, af, bf);
            *(float2*)(out + off + (size_t)u * step) = r;
        }
        off += (size_t)DEPTH * step;
    }
}

extern "C" void kernel_launch(void* const* d_in, const int* in_sizes, int n_in,
                              void* d_out, int out_size, void* d_ws, size_t ws_size,
                              hipStream_t stream) {
    const float* xq     = (const float*)d_in[0];
    const float* coeffs = (const float*)d_in[1];
    const float* knots  = (const float*)d_in[2];
    float* out = (float*)d_out;

    int K = in_sizes[2];           // 64
    int S = in_sizes[1] / K;       // 4096
    int N = in_sizes[0];           // B*S
    int B = N / S;                 // 4096

    int n_btiles = 8;              // 64 x 8 = 512 blocks -> exactly 2/CU at 1024 thr
    int b_chunk = B / n_btiles;    // 512 rows/block, 32 rows/wave
    dim3 grid(S / STILE, n_btiles);
    pchip_fused7<<<grid, BLK, 0, stream>>>(xq, coeffs, knots, out, S, b_chunk);
}

// Round 7
// 125.496 us; speedup vs baseline: 1.0681x; 1.0021x over previous
//
#include <hip/hip_runtime.h>

#define EPSF 1e-12f
#define STILE 64
#define KK 64
#define RSTR 65                 // row stride in float4 units (1040 B)
#define FSTR (4 * RSTR)         // 260 floats per coefficient row
#define BLK 1024
#define NWAVE (BLK / 64)        // 16 waves
#define PRELOOP ((STILE * KK) / BLK)  // 4
#define DEPTH 8                 // outstanding row-pair loads per wave

__device__ __forceinline__ float sgnf(float x) {
    return (x > 0.f) ? 1.f : ((x < 0.f) ? -1.f : 0.f);
}

// One ds_read_b128 per element: cf[row] holds {c0,c1,c2,c3} per interval.
__device__ __forceinline__ float eval1(float x, const float4* __restrict__ q,
                                       float af, float bf) {
    float tf = fmaf(x, af, bf);
    float tcf = fminf(fmaxf(tf, 0.f), (float)(KK - 1));
    int idx = min((int)tcf, KK - 2);
    float t = tcf - (float)idx;
    float4 c = q[idx];
    float P = fmaf(fmaf(fmaf(c.w, t, c.z), t, c.y), t, c.x);
    float w = fmaf(fmaf(t, 2.f, t), c.w, c.z + c.z);  // 3t*c3 + 2c2
    float Pp = fmaf(t, w, c.y);                       // P'(t)
    return fmaf(Pp, tf - tcf, P);                     // branch-free extrapolation
}

__global__ __launch_bounds__(BLK, 8) void pchip_fused8(
    const float* __restrict__ xq,
    const float* __restrict__ coeffs,
    const float* __restrict__ knots,
    float* __restrict__ out,
    int S, int b_chunk)
{
    __shared__ float4 cf4[STILE * RSTR];   // 66560 B: interleaved c0..c3
    __shared__ float skn[KK];
    float* cf = (float*)cf4;

    int tid = threadIdx.x;
    int s0 = blockIdx.x * STILE;
    int b0 = blockIdx.y * b_chunk;

    if (tid < KK) skn[tid] = knots[tid];
    // stage y into slot 0 (coalesced global read)
#pragma unroll
    for (int i = 0; i < PRELOOP; i++) {
        int p = tid + i * BLK;
        int sl = p >> 6, k = p & 63;
        cf[sl * FSTR + 4 * k] = coeffs[(size_t)(s0 + sl) * KK + k];
    }
    __syncthreads();
    // delta[k] into slot 3 (reads slot 0 only)
#pragma unroll
    for (int i = 0; i < PRELOOP; i++) {
        int p = tid + i * BLK;
        int sl = p >> 6, k = p & 63;
        if (k < KK - 1) {
            int ib = sl * FSTR + 4 * k;
            float hh = skn[k + 1] - skn[k];
            cf[ib + 3] = (cf[ib + 4] - cf[ib]) / (hh + EPSF);
        }
    }
    __syncthreads();
    // Fritsch-Carlson slopes d into slot 2 (reads slot 3 only)
#pragma unroll
    for (int i = 0; i < PRELOOP; i++) {
        int p = tid + i * BLK;
        int sl = p >> 6, k = p & 63;
        int rb = sl * FSTR;
        float d;
        if (k == 0) {
            float h0 = skn[1] - skn[0], h1 = skn[2] - skn[1];
            float de0 = cf[rb + 3], de1 = cf[rb + 7];
            d = ((2.f * h0 + h1) * de0 - h0 * de1) / (h0 + h1 + EPSF);
            if (sgnf(d) != sgnf(de0)) d = 0.f;
            if ((sgnf(de0) != sgnf(de1)) && (fabsf(d) > 3.f * fabsf(de0))) d = 3.f * de0;
        } else if (k == KK - 1) {
            float hn1 = skn[KK - 1] - skn[KK - 2], hn2 = skn[KK - 2] - skn[KK - 3];
            float dn1 = cf[rb + 4 * (KK - 2) + 3], dn2 = cf[rb + 4 * (KK - 3) + 3];
            d = ((2.f * hn1 + hn2) * dn1 - hn1 * dn2) / (hn1 + hn2 + EPSF);
            if (sgnf(d) != sgnf(dn1)) d = 0.f;
            if ((sgnf(dn1) != sgnf(dn2)) && (fabsf(d) > 3.f * fabsf(dn1))) d = 3.f * dn1;
        } else {
            float dprev = cf[rb + 4 * (k - 1) + 3], dnext = cf[rb + 4 * k + 3];
            float hp = skn[k] - skn[k - 1], hn = skn[k + 1] - skn[k];
            bool same = dprev * dnext > 0.f;
            float w1 = 2.f * hn + hp;
            float w2 = hn + 2.f * hp;
            float denom = w1 / (dprev + EPSF) + w2 / (dnext + EPSF);
            float dint = (w1 + w2) / (denom + EPSF);
            d = same ? dint : 0.f;
        }
        cf[rb + 4 * k + 2] = d;
    }
    __syncthreads();
    // power-basis conversion: read y(k),y(k+1),d(k),d(k+1) -> regs, sync, write c1..c3
    float c1r[PRELOOP], c2r[PRELOOP], c3r[PRELOOP];
#pragma unroll
    for (int i = 0; i < PRELOOP; i++) {
        int p = tid + i * BLK;
        int sl = p >> 6, k = p & 63;
        int kc = min(k, KK - 2);
        int ib = sl * FSTR + 4 * kc;
        float y0 = cf[ib], y1 = cf[ib + 4];
        float d0 = cf[ib + 2], d1 = cf[ib + 6];
        float h = skn[kc + 1] - skn[kc] + EPSF;
        c1r[i] = h * d0;
        c2r[i] = 3.f * (y1 - y0) - h * (2.f * d0 + d1);
        c3r[i] = 2.f * (y0 - y1) + h * (d0 + d1);
    }
    __syncthreads();
#pragma unroll
    for (int i = 0; i < PRELOOP; i++) {
        int p = tid + i * BLK;
        int sl = p >> 6, k = p & 63;
        if (k < KK - 1) {
            int ib = sl * FSTR + 4 * k;
            cf[ib + 1] = c1r[i];
            cf[ib + 2] = c2r[i];
            cf[ib + 3] = c3r[i];
        }
    }
    __syncthreads();

    // ---- evaluation sweep, SLAB-INTERLEAVED row order ----
    // Iteration m of EVERY wave covers rows b0 + m*32 + [0,32): the block's 16
    // waves form one dense 32-row slab, the 64 s-blocks complete the row width,
    // and all blocks slide their slab downward in lockstep. The aggregate DRAM
    // stream per channel becomes dense-sequential instead of 512 scattered rows
    // (aggregate-locality theory; everything else identical to R6).
    float x0d = skn[0], x1d = skn[KK - 1];
    float invh = (float)(KK - 1) / (x1d - x0d);
    float af = invh, bf = -x0d * invh;
    int wave = tid >> 6, lane = tid & 63;
    int brow = lane >> 5;            // 0..1
    int scol = (lane & 31) << 1;     // 0,2,..,62
    const float4* q0 = cf4 + scol * RSTR;
    const float4* q1 = q0 + RSTR;

    int nb = b_chunk / (2 * NWAVE);  // 16 m-iterations, 2 rows each
    size_t base = (size_t)(b0 + (wave << 1) + brow) * S + s0 + scol;
    const size_t mstep = (size_t)(2 * NWAVE) * S;   // 32 rows

    for (int m0 = 0; m0 < nb; m0 += DEPTH) {
        float2 xv[DEPTH];
#pragma unroll
        for (int u = 0; u < DEPTH; u++)
            xv[u] = *(const float2*)(xq + base + (size_t)(m0 + u) * mstep);
        __builtin_amdgcn_sched_barrier(0);   // keep all DEPTH loads issued first
#pragma unroll
        for (int u = 0; u < DEPTH; u++) {
            float2 r;
            r.x = eval1(xv[u].x, q0, af, bf);
            r.y = eval1(xv[u].y, q1, af, bf);
            *(float2*)(out + base + (size_t)(m0 + u) * mstep) = r;
        }
    }
}

extern "C" void kernel_launch(void* const* d_in, const int* in_sizes, int n_in,
                              void* d_out, int out_size, void* d_ws, size_t ws_size,
                              hipStream_t stream) {
    const float* xq     = (const float*)d_in[0];
    const float* coeffs = (const float*)d_in[1];
    const float* knots  = (const float*)d_in[2];
    float* out = (float*)d_out;

    int K = in_sizes[2];           // 64
    int S = in_sizes[1] / K;       // 4096
    int N = in_sizes[0];           // B*S
    int B = N / S;                 // 4096

    int n_btiles = 8;              // 64 x 8 = 512 blocks -> exactly 2/CU at 1024 thr
    int b_chunk = B / n_btiles;    // 512 rows/block
    dim3 grid(S / STILE, n_btiles);
    pchip_fused8<<<grid, BLK, 0, stream>>>(xq, coeffs, knots, out, S, b_chunk);
}